// Round 1
// baseline (9555.921 us; speedup 1.0000x reference)
//
#include <hip/hip_runtime.h>
#include <hip/hip_bf16.h>
#include <stdint.h>

// ---------------- problem dims ----------------
#define BB   64
#define TT   511
#define SS   512
#define DD   500
#define KXP  512          // padded input dim for layer-0 input GEMM
#define HG   384
#define G4   1536
#define HE   64
#define E4   256
#define NSEQ (BB*SS)      // 32768

typedef __hip_bfloat16 bf16;
typedef float  floatx4 __attribute__((ext_vector_type(4)));
typedef __bf16 bfrag8  __attribute__((ext_vector_type(8)));

// v_mfma_f32_16x16x32_bf16 fragment layout (gfx950):
//   A: lane l holds A[l&15][8*(l>>4)+i]      (16B contiguous along K, A stored [M][K])
//   B: lane l holds W[n=l&15][8*(l>>4)+i]    (weights stored [N][K] = torch [out][in])
//   D: lane l, reg r holds D[4*(l>>4)+r][l&15]
static __device__ __forceinline__ floatx4 MFMA16(bfrag8 a, bfrag8 b, floatx4 c){
  return __builtin_amdgcn_mfma_f32_16x16x32_bf16(a, b, c, 0, 0, 0);
}
static __device__ __forceinline__ float sigm_(float x){ return 1.f/(1.f + __expf(-x)); }
static __device__ __forceinline__ float tanh_(float x){
  x = fminf(fmaxf(x, -15.f), 15.f);
  float e = __expf(2.f*x);
  return (e - 1.f)/(e + 1.f);
}

// ---------------------------------------------------------------------------
// prep: build padded bf16 X = [sentinel ; concat(input, tag)]  -> [32768][512]
// ---------------------------------------------------------------------------
__global__ __launch_bounds__(256) void prep_x(const float* __restrict__ input,
    const float* __restrict__ tag, const float* __restrict__ sent,
    bf16* __restrict__ Xb)
{
  const size_t stp = (size_t)gridDim.x * blockDim.x;
  for (size_t i = (size_t)blockIdx.x*blockDim.x + threadIdx.x; i < (size_t)NSEQ*KXP; i += stp){
    int m = (int)(i >> 9), k = (int)(i & 511);
    int b = m >> 9, s = m & 511;
    float v;
    if (k >= DD)        v = 0.f;
    else if (s == 0)    v = sent[k];
    else if (k < 400)   v = input[(size_t)(b*TT + s-1)*400 + k];
    else                v = tag  [(size_t)(b*TT + s-1)*100 + (k-400)];
    Xb[i] = __float2bfloat16(v);
  }
}

// ---------------------------------------------------------------------------
// prep: weight conversions / bias folds / state zeroing
// ---------------------------------------------------------------------------
__global__ __launch_bounds__(256) void prep_w(
  const float* __restrict__ gWih0, const float* __restrict__ gWhh0,
  const float* __restrict__ gbih0, const float* __restrict__ gbhh0,
  const float* __restrict__ gWih1, const float* __restrict__ gWhh1,
  const float* __restrict__ gbih1, const float* __restrict__ gbhh1,
  const float* __restrict__ eWih0, const float* __restrict__ eWhh0,
  const float* __restrict__ ebih0, const float* __restrict__ ebhh0,
  const float* __restrict__ eWih1, const float* __restrict__ eWhh1,
  const float* __restrict__ ebih1, const float* __restrict__ ebhh1,
  const float* __restrict__ g2eW, const float* __restrict__ htW, const float* __restrict__ dtW,
  bf16* __restrict__ Wih0b, bf16* __restrict__ Whh0b, bf16* __restrict__ W1cat,
  float* __restrict__ gb0, float* __restrict__ gb1,
  bf16* __restrict__ eW0b, bf16* __restrict__ eW1ab, bf16* __restrict__ eW1bb,
  float* __restrict__ eb0, float* __restrict__ eb1, float* __restrict__ ew0cv,
  bf16* __restrict__ g2eWb, bf16* __restrict__ htWb, bf16* __restrict__ dtWb,
  float* __restrict__ c0, float* __restrict__ c1)
{
  const int st = blockIdx.x*blockDim.x + threadIdx.x;
  const int gs = gridDim.x*blockDim.x;
  for (int i=st; i<G4*KXP; i+=gs){ int r=i>>9, k=i&511;
      Wih0b[i] = __float2bfloat16(k<DD ? gWih0[r*DD+k] : 0.f); }
  for (int i=st; i<G4*HG; i+=gs) Whh0b[i] = __float2bfloat16(gWhh0[i]);
  for (int i=st; i<G4*768; i+=gs){ int r=i/768, k=i-r*768;
      W1cat[i] = __float2bfloat16(k<HG ? gWih1[r*HG+k] : gWhh1[r*HG+(k-HG)]); }
  for (int i=st; i<G4; i+=gs){ gb0[i]=gbih0[i]+gbhh0[i]; gb1[i]=gbih1[i]+gbhh1[i]; }
  for (int i=st; i<E4*HE; i+=gs){ eW0b[i]=__float2bfloat16(eWhh0[i]);
      eW1ab[i]=__float2bfloat16(eWih1[i]); eW1bb[i]=__float2bfloat16(eWhh1[i]); }
  for (int i=st; i<E4; i+=gs){ eb0[i]=ebih0[i]+ebhh0[i]; eb1[i]=ebih1[i]+ebhh1[i];
      ew0cv[i]=eWih0[i]; }
  for (int i=st; i<HE*HG; i+=gs) g2eWb[i]=__float2bfloat16(g2eW[i]);
  for (int i=st; i<128*HG; i+=gs){
      htWb[i] = __float2bfloat16(i<100*HG ? htW[i] : 0.f);
      dtWb[i] = __float2bfloat16(i<100*HG ? dtW[i] : 0.f); }
  for (int i=st; i<BB*HG; i+=gs){ c0[i]=0.f; c1[i]=0.f; }
}

// ---------------------------------------------------------------------------
// generic MFMA GEMM:  out[M][N] = epi( A[M][KTOT] @ Wt[N][KTOT]^T )
//   EPI 0: +bias, store bf16 (ld=Nreal)                     -> G0
//   EPI 1: *maskrow +bias, store bf16                       -> proj
//   EPI 2: *maskrow +bias, elu, store f32, guard col<Nreal  -> head/dep tag
// ---------------------------------------------------------------------------
template<int KTOT,int BN,int WAVES_M,int WAVES_N,int EPI>
__global__ __launch_bounds__(256) void gemm_mfma(
    const bf16* __restrict__ A, const bf16* __restrict__ Wt,
    const float* __restrict__ bias, const int* __restrict__ mask,
    void* __restrict__ outp, int Nreal)
{
  constexpr int WMT = 128/(WAVES_M*16);
  constexpr int WNT = BN /(WAVES_N*16);
  __shared__ alignas(16) bf16 As[128][32];
  __shared__ alignas(16) bf16 Bs[BN][32];
  const int tid = threadIdx.x;
  const int bm = blockIdx.x & 255, bn = blockIdx.x >> 8;
  const int m0 = bm*128, n0 = bn*BN;
  const int wid = tid>>6, l = tid&63, lj = l&15, lq = l>>4;
  const int wm = wid / WAVES_N, wn = wid % WAVES_N;
  floatx4 acc[WMT][WNT] = {};
  for (int k0 = 0; k0 < KTOT; k0 += 32){
    __syncthreads();
    for (int c = tid; c < 128*4; c += 256){
      int row = c>>2, ch = c&3;
      *(uint4*)&As[row][ch*8] = *(const uint4*)&A[(size_t)(m0+row)*KTOT + k0 + ch*8];
    }
    for (int c = tid; c < BN*4; c += 256){
      int row = c>>2, ch = c&3;
      *(uint4*)&Bs[row][ch*8] = *(const uint4*)&Wt[(size_t)(n0+row)*KTOT + k0 + ch*8];
    }
    __syncthreads();
    bfrag8 af[WMT]; bfrag8 bfr[WNT];
    #pragma unroll
    for (int mi=0;mi<WMT;++mi) af[mi]  = *(const bfrag8*)&As[wm*WMT*16 + mi*16 + lj][lq*8];
    #pragma unroll
    for (int ni=0;ni<WNT;++ni) bfr[ni] = *(const bfrag8*)&Bs[wn*WNT*16 + ni*16 + lj][lq*8];
    #pragma unroll
    for (int mi=0;mi<WMT;++mi)
      #pragma unroll
      for (int ni=0;ni<WNT;++ni)
        acc[mi][ni] = MFMA16(af[mi], bfr[ni], acc[mi][ni]);
  }
  #pragma unroll
  for (int mi=0;mi<WMT;++mi){
    #pragma unroll
    for (int ni=0;ni<WNT;++ni){
      #pragma unroll
      for (int r=0;r<4;++r){
        int grow = m0 + wm*WMT*16 + mi*16 + 4*lq + r;
        int gcol = n0 + wn*WNT*16 + ni*16 + lj;
        float v = acc[mi][ni][r];
        if (EPI == 0){
          v += bias[gcol];
          ((bf16*)outp)[(size_t)grow*Nreal + gcol] = __float2bfloat16(v);
        } else {
          int s = grow & 511, b = grow >> 9;
          float mk = (s==0) ? 1.f : (float)mask[b*TT + s - 1];
          v = v*mk + bias[gcol];
          if (EPI == 1){
            ((bf16*)outp)[(size_t)grow*Nreal + gcol] = __float2bfloat16(v);
          } else {
            v = v > 0.f ? v : expm1f(v);
            if (gcol < Nreal) ((float*)outp)[(size_t)grow*Nreal + gcol] = v;
          }
        }
      }
    }
  }
}

// ---------------------------------------------------------------------------
// one graph-LSTM time step: blocks 0..23 = layer0 step t, blocks 24..47 =
// layer1 step t-1 (pipelined; layer1 consumes h0seq[t-1] from prior launch).
// h0seq layout [t][b][384]; h1seq layout [b][t][384] (= row-major [32768][384]).
// ---------------------------------------------------------------------------
__global__ __launch_bounds__(256) void graph_step(int t,
    const bf16* __restrict__ G0, const bf16* __restrict__ Whh0b,
    const bf16* __restrict__ W1cat, const float* __restrict__ gb1,
    bf16* __restrict__ h0seq, bf16* __restrict__ h1seq,
    float* __restrict__ c0, float* __restrict__ c1)
{
  const int tid = threadIdx.x;
  const int wg = blockIdx.x*4 + (tid>>6);
  const int l = tid&63, lj = l&15, lq = l>>4;
  if (wg < 96){
    if (t >= SS) return;
    const int mi = wg & 3, jt = wg >> 2;
    const int m0 = mi*16, j0 = jt*16;
    floatx4 acc[4] = {};
    if (t > 0){
      for (int ks=0; ks<12; ++ks){
        int k = ks*32;
        bfrag8 a = *(const bfrag8*)&h0seq[(size_t)((t-1)*BB + m0 + lj)*HG + k + lq*8];
        #pragma unroll
        for (int g=0; g<4; ++g){
          bfrag8 b = *(const bfrag8*)&Whh0b[(size_t)(g*HG + j0 + lj)*HG + k + lq*8];
          acc[g] = MFMA16(a, b, acc[g]);
        }
      }
    }
    #pragma unroll
    for (int r=0; r<4; ++r){
      int bb = m0 + 4*lq + r;
      int j  = j0 + lj;
      size_t grow = (size_t)(bb*SS + t)*G4;
      float pi = acc[0][r] + __bfloat162float(G0[grow + 0*HG + j]);
      float pf = acc[1][r] + __bfloat162float(G0[grow + 1*HG + j]);
      float pg = acc[2][r] + __bfloat162float(G0[grow + 2*HG + j]);
      float po = acc[3][r] + __bfloat162float(G0[grow + 3*HG + j]);
      float i_=sigm_(pi), f_=sigm_(pf), g_=tanh_(pg), o_=sigm_(po);
      int ci = bb*HG + j;
      float c = c0[ci]; c = f_*c + i_*g_; c0[ci] = c;
      float h = o_*tanh_(c);
      h0seq[(size_t)(t*BB + bb)*HG + j] = __float2bfloat16(h);
    }
  } else {
    if (t < 1) return;
    const int u = t-1;
    const int w = wg - 96;
    const int mi = w & 3, jt = w >> 2;
    const int m0 = mi*16, j0 = jt*16;
    floatx4 acc[4] = {};
    for (int ks=0; ks<24; ++ks){
      int k = ks*32;
      if (k >= HG && u == 0) break;     // h1[-1] = 0
      bfrag8 a;
      if (k < HG) a = *(const bfrag8*)&h0seq[(size_t)(u*BB + m0 + lj)*HG + k + lq*8];
      else        a = *(const bfrag8*)&h1seq[(size_t)((m0 + lj)*SS + (u-1))*HG + (k-HG) + lq*8];
      #pragma unroll
      for (int g=0; g<4; ++g){
        bfrag8 b = *(const bfrag8*)&W1cat[(size_t)(g*HG + j0 + lj)*768 + k + lq*8];
        acc[g] = MFMA16(a, b, acc[g]);
      }
    }
    #pragma unroll
    for (int r=0; r<4; ++r){
      int bb = m0 + 4*lq + r;
      int j  = j0 + lj;
      float pi = acc[0][r] + gb1[0*HG + j];
      float pf = acc[1][r] + gb1[1*HG + j];
      float pg = acc[2][r] + gb1[2*HG + j];
      float po = acc[3][r] + gb1[3*HG + j];
      float i_=sigm_(pi), f_=sigm_(pf), g_=tanh_(pg), o_=sigm_(po);
      int ci = bb*HG + j;
      float c = c1[ci]; c = f_*c + i_*g_; c1[ci] = c;
      float h = o_*tanh_(c);
      h1seq[(size_t)(bb*SS + u)*HG + j] = __float2bfloat16(h);   // unmasked; consumers mask
    }
  }
}

// ---------------------------------------------------------------------------
// fused 2-layer edge LSTM, 33 steps, + cls dot, banded arc writeback.
// WG = 4 waves = 16 sequences; wave w owns hidden cols [16w,16w+16).
// Recurrent weights live in registers (24 frags/lane); h exchanged via LDS.
// ---------------------------------------------------------------------------
__global__ __launch_bounds__(256) void edge_lstm(
    const bf16* __restrict__ projb,
    const bf16* __restrict__ eW0b, const bf16* __restrict__ eW1ab, const bf16* __restrict__ eW1bb,
    const float* __restrict__ eb0, const float* __restrict__ eb1, const float* __restrict__ ew0c,
    const float* __restrict__ clsW, const float* __restrict__ clsb_p, const float* __restrict__ bos_p,
    const int* __restrict__ heads, float* __restrict__ arc)
{
  __shared__ alignas(16) bf16 hbuf0[16][72];   // +16B row pad -> 2-way banks (free)
  __shared__ alignas(16) bf16 hbuf1[16][72];
  __shared__ float lbuf[4][16];
  const int tid = threadIdx.x, w = tid>>6, l = tid&63, lj = l&15, lq = l>>4;
  const int seq0 = blockIdx.x * 16;
  const int jglob = w*16 + lj;
  for (int i = tid; i < 16*64; i += 256){
    int sl = i >> 6, jj = i & 63;
    bf16 v = projb[(size_t)(seq0+sl)*HE + jj];
    hbuf0[sl][jj] = v; hbuf1[sl][jj] = v;      // h-init = proj for both layers
  }
  bfrag8 W0f[4][2], W1af[4][2], W1bf[4][2];
  #pragma unroll
  for (int g=0; g<4; ++g){
    #pragma unroll
    for (int kk=0; kk<2; ++kk){
      size_t offw = (size_t)(g*HE + jglob)*HE + kk*32 + lq*8;
      W0f [g][kk] = *(const bfrag8*)&eW0b [offw];
      W1af[g][kk] = *(const bfrag8*)&eW1ab[offw];
      W1bf[g][kk] = *(const bfrag8*)&eW1bb[offw];
    }
  }
  float ebr0[4], ebr1[4], ewr[4];
  #pragma unroll
  for (int g=0; g<4; ++g){ ebr0[g]=eb0[g*HE+jglob]; ebr1[g]=eb1[g*HE+jglob]; ewr[g]=ew0c[g*HE+jglob]; }
  const float clswj = clsW[jglob];
  const float bos = bos_p[0], clsb = clsb_p[0];
  int hd[4]; float c0r[4]={0,0,0,0}, c1r[4]={0,0,0,0};
  #pragma unroll
  for (int r=0;r<4;++r){
    int sq = seq0 + 4*lq + r;
    int b = sq >> 9, s = sq & 511;
    hd[r] = (s==0) ? 0 : heads[b*TT + s - 1];
  }
  __syncthreads();
  for (int j=0; j<33; ++j){
    // ---- layer 0 ----
    floatx4 acc0[4] = {};
    bfrag8 a0[2];
    #pragma unroll
    for (int kk=0; kk<2; ++kk)
      a0[kk] = *(const bfrag8*)((const char*)&hbuf0[0][0] + lj*144 + kk*64 + lq*16);
    #pragma unroll
    for (int g=0; g<4; ++g)
      #pragma unroll
      for (int kk=0; kk<2; ++kk)
        acc0[g] = MFMA16(a0[kk], W0f[g][kk], acc0[g]);
    __syncthreads();                       // (a) all hbuf0 reads done
    float h0v[4];
    #pragma unroll
    for (int r=0;r<4;++r){
      float x = (j==0) ? bos : ((hd[r] == j-1) ? 1.f : 0.f);
      float pi = acc0[0][r] + ebr0[0] + x*ewr[0];
      float pf = acc0[1][r] + ebr0[1] + x*ewr[1];
      float pg = acc0[2][r] + ebr0[2] + x*ewr[2];
      float po = acc0[3][r] + ebr0[3] + x*ewr[3];
      float i_=sigm_(pi), f_=sigm_(pf), g_=tanh_(pg), o_=sigm_(po);
      c0r[r] = f_*c0r[r] + i_*g_;
      h0v[r] = o_*tanh_(c0r[r]);
    }
    #pragma unroll
    for (int r=0;r<4;++r) hbuf0[4*lq + r][jglob] = __float2bfloat16(h0v[r]);
    __syncthreads();                       // (b) h0(t) visible
    // ---- layer 1 (input = h0(t), recurrent = h1(t-1)) ----
    floatx4 acc1[4] = {};
    bfrag8 a1[2], a2[2];
    #pragma unroll
    for (int kk=0;kk<2;++kk){
      a1[kk] = *(const bfrag8*)((const char*)&hbuf0[0][0] + lj*144 + kk*64 + lq*16);
      a2[kk] = *(const bfrag8*)((const char*)&hbuf1[0][0] + lj*144 + kk*64 + lq*16);
    }
    #pragma unroll
    for (int g=0; g<4; ++g){
      #pragma unroll
      for (int kk=0;kk<2;++kk){
        acc1[g] = MFMA16(a1[kk], W1af[g][kk], acc1[g]);
        acc1[g] = MFMA16(a2[kk], W1bf[g][kk], acc1[g]);
      }
    }
    __syncthreads();                       // (c) hbuf1 reads done
    float p[4];
    #pragma unroll
    for (int r=0;r<4;++r){
      float pi = acc1[0][r] + ebr1[0];
      float pf = acc1[1][r] + ebr1[1];
      float pg = acc1[2][r] + ebr1[2];
      float po = acc1[3][r] + ebr1[3];
      float i_=sigm_(pi), f_=sigm_(pf), g_=tanh_(pg), o_=sigm_(po);
      c1r[r] = f_*c1r[r] + i_*g_;
      float h1 = o_*tanh_(c1r[r]);
      hbuf1[4*lq + r][jglob] = __float2bfloat16(h1);
      p[r] = h1 * clswj;                   // f32 partial of cls dot
    }
    #pragma unroll
    for (int mk=1; mk<16; mk<<=1)
      #pragma unroll
      for (int r=0;r<4;++r) p[r] += __shfl_xor(p[r], mk, 64);
    if (lj == 0){
      #pragma unroll
      for (int r=0;r<4;++r) lbuf[w][4*lq + r] = p[r];
    }
    __syncthreads();                       // (d)
    if (tid < 16 && j >= 1){
      int sq = seq0 + tid;
      float v = lbuf[0][tid] + lbuf[1][tid] + lbuf[2][tid] + lbuf[3][tid] + clsb;
      arc[(size_t)sq*SS + (j-1)] = v;      // arc_logits[b][s][j-1]
    }
  }
}

// ---------------------------------------------------------------------------
extern "C" void kernel_launch(void* const* d_in, const int* in_sizes, int n_in,
                              void* d_out, int out_size, void* d_ws, size_t ws_size,
                              hipStream_t stream)
{
  const float* input = (const float*)d_in[0];
  const float* tag   = (const float*)d_in[1];
  const int*   mask  = (const int*)  d_in[2];
  const int*   heads = (const int*)  d_in[3];
  const float* sent  = (const float*)d_in[4];
  const float* bosp  = (const float*)d_in[5];
  const float* gWih0 = (const float*)d_in[6];
  const float* gWhh0 = (const float*)d_in[7];
  const float* gbih0 = (const float*)d_in[8];
  const float* gbhh0 = (const float*)d_in[9];
  const float* gWih1 = (const float*)d_in[10];
  const float* gWhh1 = (const float*)d_in[11];
  const float* gbih1 = (const float*)d_in[12];
  const float* gbhh1 = (const float*)d_in[13];
  const float* eWih0 = (const float*)d_in[14];
  const float* eWhh0 = (const float*)d_in[15];
  const float* ebih0 = (const float*)d_in[16];
  const float* ebhh0 = (const float*)d_in[17];
  const float* eWih1 = (const float*)d_in[18];
  const float* eWhh1 = (const float*)d_in[19];
  const float* ebih1 = (const float*)d_in[20];
  const float* ebhh1 = (const float*)d_in[21];
  const float* g2eW  = (const float*)d_in[22];
  const float* g2eb  = (const float*)d_in[23];
  const float* clsW  = (const float*)d_in[24];
  const float* clsb  = (const float*)d_in[25];
  const float* htW   = (const float*)d_in[26];
  const float* htb   = (const float*)d_in[27];
  const float* dtW   = (const float*)d_in[28];
  const float* dtb   = (const float*)d_in[29];

  char* wsb = (char*)d_ws;
  size_t off = 0;
  auto take = [&](size_t bytes)->char* {
    char* p = wsb + off;
    off = (off + bytes + 255) & ~(size_t)255;
    return p;
  };
  bf16*  Xb     = (bf16*) take((size_t)NSEQ*KXP*2);   // 33.6 MB
  bf16*  Wih0b  = (bf16*) take((size_t)G4*KXP*2);
  bf16*  Whh0b  = (bf16*) take((size_t)G4*HG*2);
  bf16*  W1cat  = (bf16*) take((size_t)G4*768*2);     // [Wih1 | Whh1]
  float* gb0    = (float*)take(G4*4);
  float* gb1    = (float*)take(G4*4);
  bf16*  G0     = (bf16*) take((size_t)NSEQ*G4*2);    // 100.7 MB input-gate precompute
  bf16*  h0seq  = (bf16*) take((size_t)SS*BB*HG*2);   // 25.2 MB  [t][b][384]
  bf16*  h1seq  = (bf16*) take((size_t)BB*SS*HG*2);   // 25.2 MB  [b][t][384]
  float* c0w    = (float*)take(BB*HG*4);
  float* c1w    = (float*)take(BB*HG*4);
  bf16*  projb  = (bf16*) take((size_t)NSEQ*HE*2);
  bf16*  eW0b   = (bf16*) take(E4*HE*2);
  bf16*  eW1ab  = (bf16*) take(E4*HE*2);
  bf16*  eW1bb  = (bf16*) take(E4*HE*2);
  float* eb0w   = (float*)take(E4*4);
  float* eb1w   = (float*)take(E4*4);
  float* ew0cw  = (float*)take(E4*4);
  bf16*  g2eWb  = (bf16*) take(HE*HG*2);
  bf16*  htWb   = (bf16*) take(128*HG*2);             // zero-padded rows 100..127
  bf16*  dtWb   = (bf16*) take(128*HG*2);

  // arc_logits zero fill (band cols >= 32 stay 0; cols < 32 overwritten by edge_lstm)
  (void)hipMemsetAsync(d_out, 0, (size_t)16777216*4, stream);

  prep_x<<<2048,256,0,stream>>>(input, tag, sent, Xb);
  prep_w<<<512,256,0,stream>>>(gWih0,gWhh0,gbih0,gbhh0,gWih1,gWhh1,gbih1,gbhh1,
                               eWih0,eWhh0,ebih0,ebhh0,eWih1,eWhh1,ebih1,ebhh1,
                               g2eW,htW,dtW,
                               Wih0b,Whh0b,W1cat,gb0,gb1,eW0b,eW1ab,eW1bb,
                               eb0w,eb1w,ew0cw,g2eWb,htWb,dtWb,c0w,c1w);

  // layer-0 input gates: G0 = X @ Wih0^T + (bih0+bhh0)
  gemm_mfma<KXP,128,2,2,0><<<3072,256,0,stream>>>(Xb, Wih0b, gb0, nullptr, (void*)G0, G4);

  // graph LSTM recurrence: layer0 step t + layer1 step t-1 per launch
  for (int t=0; t<=SS; ++t)
    graph_step<<<48,256,0,stream>>>(t, G0, Whh0b, W1cat, gb1, h0seq, h1seq, c0w, c1w);

  // proj = mask * (graph_state @ g2e_W^T) + g2e_b   -> bf16
  gemm_mfma<HG,64,4,1,1><<<256,256,0,stream>>>(h1seq, g2eWb, g2eb, mask, (void*)projb, HE);

  // banded teacher-forced edge LSTM + cls + arc writeback
  edge_lstm<<<2048,256,0,stream>>>(projb, eW0b, eW1ab, eW1bb, eb0w, eb1w, ew0cw,
                                   clsW, clsb, bosp, heads, (float*)d_out);

  // tag feedforwards: elu(mask*(graph_state @ W^T) + b)
  gemm_mfma<HG,128,2,2,2><<<256,256,0,stream>>>(h1seq, htWb, htb, mask,
      (void*)((float*)d_out + 16777216), 100);
  gemm_mfma<HG,128,2,2,2><<<256,256,0,stream>>>(h1seq, dtWb, dtb, mask,
      (void*)((float*)d_out + 16777216 + 3276800), 100);
}

// Round 2
// 6866.479 us; speedup vs baseline: 1.3917x; 1.3917x over previous
//
#include <hip/hip_runtime.h>
#include <hip/hip_bf16.h>
#include <stdint.h>

// ---------------- problem dims ----------------
#define BB   64
#define TT   511
#define SS   512
#define DD   500
#define KXP  512          // padded input dim for layer-0 input GEMM
#define HG   384
#define G4   1536
#define HE   64
#define E4   256
#define NSEQ (BB*SS)      // 32768

typedef __hip_bfloat16 bf16;
typedef float  floatx4 __attribute__((ext_vector_type(4)));
typedef __bf16 bfrag8  __attribute__((ext_vector_type(8)));

// v_mfma_f32_16x16x32_bf16 fragment layout (gfx950):
//   A: lane l holds A[l&15][8*(l>>4)+i]      (16B contiguous along K, A stored [M][K])
//   B: lane l holds W[n=l&15][8*(l>>4)+i]    (weights stored [N][K] = torch [out][in])
//   D: lane l, reg r holds D[4*(l>>4)+r][l&15]
static __device__ __forceinline__ floatx4 MFMA16(bfrag8 a, bfrag8 b, floatx4 c){
  return __builtin_amdgcn_mfma_f32_16x16x32_bf16(a, b, c, 0, 0, 0);
}
static __device__ __forceinline__ float sigm_(float x){ return 1.f/(1.f + __expf(-x)); }
static __device__ __forceinline__ float tanh_(float x){
  x = fminf(fmaxf(x, -15.f), 15.f);
  float e = __expf(2.f*x);
  return (e - 1.f)/(e + 1.f);
}
static __device__ __forceinline__ float b2f(unsigned short u){
  union { unsigned int i; float f; } x; x.i = ((unsigned int)u)<<16; return x.f;
}

// ---------------------------------------------------------------------------
// prep: build padded bf16 X = [sentinel ; concat(input, tag)]  -> [32768][512]
// ---------------------------------------------------------------------------
__global__ __launch_bounds__(256) void prep_x(const float* __restrict__ input,
    const float* __restrict__ tag, const float* __restrict__ sent,
    bf16* __restrict__ Xb)
{
  const size_t stp = (size_t)gridDim.x * blockDim.x;
  for (size_t i = (size_t)blockIdx.x*blockDim.x + threadIdx.x; i < (size_t)NSEQ*KXP; i += stp){
    int m = (int)(i >> 9), k = (int)(i & 511);
    int b = m >> 9, s = m & 511;
    float v;
    if (k >= DD)        v = 0.f;
    else if (s == 0)    v = sent[k];
    else if (k < 400)   v = input[(size_t)(b*TT + s-1)*400 + k];
    else                v = tag  [(size_t)(b*TT + s-1)*100 + (k-400)];
    Xb[i] = __float2bfloat16(v);
  }
}

// ---------------------------------------------------------------------------
// prep: weight conversions with gate interleave n=4j+g, bias folds
// ---------------------------------------------------------------------------
__global__ __launch_bounds__(256) void prep_w(
  const float* __restrict__ gWih0, const float* __restrict__ gWhh0,
  const float* __restrict__ gbih0, const float* __restrict__ gbhh0,
  const float* __restrict__ gWih1, const float* __restrict__ gWhh1,
  const float* __restrict__ gbih1, const float* __restrict__ gbhh1,
  const float* __restrict__ eWih0, const float* __restrict__ eWhh0,
  const float* __restrict__ ebih0, const float* __restrict__ ebhh0,
  const float* __restrict__ eWih1, const float* __restrict__ eWhh1,
  const float* __restrict__ ebih1, const float* __restrict__ ebhh1,
  const float* __restrict__ g2eW, const float* __restrict__ htW, const float* __restrict__ dtW,
  bf16* __restrict__ W0i, bf16* __restrict__ W0r, bf16* __restrict__ W1c,
  float* __restrict__ gb0, float* __restrict__ gb1,
  bf16* __restrict__ eW0b, bf16* __restrict__ eW1ab, bf16* __restrict__ eW1bb,
  float* __restrict__ eb0, float* __restrict__ eb1, float* __restrict__ ew0cv,
  bf16* __restrict__ g2eWb, bf16* __restrict__ htWb, bf16* __restrict__ dtWb)
{
  const int st = blockIdx.x*blockDim.x + threadIdx.x;
  const int gs = gridDim.x*blockDim.x;
  // layer-0 input weights, rows interleaved n=4j+g, K padded to 512
  for (int i=st; i<G4*KXP; i+=gs){ int n=i>>9, k=i&511; int j=n>>2, g=n&3;
      W0i[i] = __float2bfloat16(k<DD ? gWih0[(size_t)(g*HG+j)*DD+k] : 0.f); }
  // layer-0 recurrent weights interleaved [1536][384]
  for (int i=st; i<G4*HG; i+=gs){ int n=i/HG, k=i-n*HG; int j=n>>2, g=n&3;
      W0r[i] = __float2bfloat16(gWhh0[(size_t)(g*HG+j)*HG+k]); }
  // layer-1 concat [Wih1|Whh1] interleaved [1536][768]
  for (int i=st; i<G4*768; i+=gs){ int n=i/768, k=i-n*768; int j=n>>2, g=n&3;
      W1c[i] = __float2bfloat16(k<HG ? gWih1[(size_t)(g*HG+j)*HG+k]
                                     : gWhh1[(size_t)(g*HG+j)*HG+(k-HG)]); }
  for (int i=st; i<G4; i+=gs){ int j=i>>2, g=i&3; int s=g*HG+j;
      gb0[i]=gbih0[s]+gbhh0[s]; gb1[i]=gbih1[s]+gbhh1[s]; }
  // edge LSTM weights (layouts unchanged from R1)
  for (int i=st; i<E4*HE; i+=gs){ eW0b[i]=__float2bfloat16(eWhh0[i]);
      eW1ab[i]=__float2bfloat16(eWih1[i]); eW1bb[i]=__float2bfloat16(eWhh1[i]); }
  for (int i=st; i<E4; i+=gs){ eb0[i]=ebih0[i]+ebhh0[i]; eb1[i]=ebih1[i]+ebhh1[i];
      ew0cv[i]=eWih0[i]; }
  for (int i=st; i<HE*HG; i+=gs) g2eWb[i]=__float2bfloat16(g2eW[i]);
  for (int i=st; i<128*HG; i+=gs){
      htWb[i] = __float2bfloat16(i<100*HG ? htW[i] : 0.f);
      dtWb[i] = __float2bfloat16(i<100*HG ? dtW[i] : 0.f); }
}

// ---------------------------------------------------------------------------
// generic MFMA GEMM:  out[M][N] = epi( A[M][KTOT] @ Wt[N][KTOT]^T )
//   EPI 0: +bias, store bf16 (ld=Nreal)
//   EPI 3: +bias, store bf16 TRANSPOSED time-major: out[(s*64+b)*1536 + col]
//   EPI 1: *maskrow +bias, store bf16
//   EPI 2: *maskrow +bias, elu, store f32, guard col<Nreal
// ---------------------------------------------------------------------------
template<int KTOT,int BN,int WAVES_M,int WAVES_N,int EPI>
__global__ __launch_bounds__(256) void gemm_mfma(
    const bf16* __restrict__ A, const bf16* __restrict__ Wt,
    const float* __restrict__ bias, const int* __restrict__ mask,
    void* __restrict__ outp, int Nreal)
{
  constexpr int WMT = 128/(WAVES_M*16);
  constexpr int WNT = BN /(WAVES_N*16);
  __shared__ alignas(16) bf16 As[128][32];
  __shared__ alignas(16) bf16 Bs[BN][32];
  const int tid = threadIdx.x;
  const int bm = blockIdx.x & 255, bn = blockIdx.x >> 8;
  const int m0 = bm*128, n0 = bn*BN;
  const int wid = tid>>6, l = tid&63, lj = l&15, lq = l>>4;
  const int wm = wid / WAVES_N, wn = wid % WAVES_N;
  floatx4 acc[WMT][WNT] = {};
  for (int k0 = 0; k0 < KTOT; k0 += 32){
    __syncthreads();
    for (int c = tid; c < 128*4; c += 256){
      int row = c>>2, ch = c&3;
      *(uint4*)&As[row][ch*8] = *(const uint4*)&A[(size_t)(m0+row)*KTOT + k0 + ch*8];
    }
    for (int c = tid; c < BN*4; c += 256){
      int row = c>>2, ch = c&3;
      *(uint4*)&Bs[row][ch*8] = *(const uint4*)&Wt[(size_t)(n0+row)*KTOT + k0 + ch*8];
    }
    __syncthreads();
    bfrag8 af[WMT]; bfrag8 bfr[WNT];
    #pragma unroll
    for (int mi=0;mi<WMT;++mi) af[mi]  = *(const bfrag8*)&As[wm*WMT*16 + mi*16 + lj][lq*8];
    #pragma unroll
    for (int ni=0;ni<WNT;++ni) bfr[ni] = *(const bfrag8*)&Bs[wn*WNT*16 + ni*16 + lj][lq*8];
    #pragma unroll
    for (int mi=0;mi<WMT;++mi)
      #pragma unroll
      for (int ni=0;ni<WNT;++ni)
        acc[mi][ni] = MFMA16(af[mi], bfr[ni], acc[mi][ni]);
  }
  #pragma unroll
  for (int mi=0;mi<WMT;++mi){
    #pragma unroll
    for (int ni=0;ni<WNT;++ni){
      #pragma unroll
      for (int r=0;r<4;++r){
        int grow = m0 + wm*WMT*16 + mi*16 + 4*lq + r;
        int gcol = n0 + wn*WNT*16 + ni*16 + lj;
        float v = acc[mi][ni][r];
        if (EPI == 0){
          v += bias[gcol];
          ((bf16*)outp)[(size_t)grow*Nreal + gcol] = __float2bfloat16(v);
        } else if (EPI == 3){
          v += bias[gcol];
          int s = grow & 511, b = grow >> 9;
          ((bf16*)outp)[((size_t)s*BB + b)*G4 + gcol] = __float2bfloat16(v);
        } else {
          int s = grow & 511, b = grow >> 9;
          float mk = (s==0) ? 1.f : (float)mask[b*TT + s - 1];
          v = v*mk + bias[gcol];
          if (EPI == 1){
            ((bf16*)outp)[(size_t)grow*Nreal + gcol] = __float2bfloat16(v);
          } else {
            v = v > 0.f ? v : expm1f(v);
            if (gcol < Nreal) ((float*)outp)[(size_t)grow*Nreal + gcol] = v;
          }
        }
      }
    }
  }
}

// ---------------------------------------------------------------------------
// persistent graph-LSTM recurrence: 96 blocks x 256 threads, 513 grid barriers.
// blocks 0..47 layer0 (step t), blocks 48..95 layer1 (step t-1, pipelined).
// Gate rows interleaved n=4j+g; weights in registers; c-state in registers.
// h0 exchanged via 2-slot global ring; h1 written to h1seq [b][t][384].
// ---------------------------------------------------------------------------
__device__ __forceinline__ void grid_barrier(unsigned int* ctrs, int it, int bid, int tid){
  asm volatile("s_waitcnt vmcnt(0) lgkmcnt(0)" ::: "memory");
  __syncthreads();
  if (tid == 0){
    __threadfence();  // release: make our h stores agent-visible
    __hip_atomic_fetch_add(&ctrs[(bid&7)*64], 1u, __ATOMIC_RELAXED, __HIP_MEMORY_SCOPE_AGENT);
  }
  if (tid < 8){
    const unsigned int tgt = (unsigned int)(it+1)*12u;   // 96 blocks / 8 counters
    while (__hip_atomic_load(&ctrs[tid*64], __ATOMIC_RELAXED, __HIP_MEMORY_SCOPE_AGENT) < tgt)
      __builtin_amdgcn_s_sleep(1);
  }
  __syncthreads();
  if (tid == 0) __threadfence();  // acquire: invalidate stale L1/L2
  __syncthreads();
}

template<int IS1>
__device__ __forceinline__ void rnn_body(int bid, int tid,
    const bf16* __restrict__ G0t, const bf16* __restrict__ Wsrc,
    const float* __restrict__ gb1,
    bf16* __restrict__ h0r, bf16* __restrict__ h1seq, unsigned int* ctrs)
{
  constexpr int KF = IS1 ? 24 : 12;
  constexpr int KW = IS1 ? 768 : 384;
  const int bl = IS1 ? bid-48 : bid;
  const int w = tid>>6, l = tid&63, lj = l&15, lq = l>>4;
  const int m0 = w*16;          // wave = batch tile
  const int n0 = bl*32;         // block's 2 N-tiles: gate cols [n0, n0+32)
  const int a  = (l&15)>>2;     // quad's hidden index within tile
  // recurrent weights in registers (layer1: 192 VGPR)
  bfrag8 Wf0[KF], Wf1[KF];
  #pragma unroll
  for (int kf=0; kf<KF; ++kf){
    Wf0[kf] = *(const bfrag8*)&Wsrc[(size_t)(n0 + lj)*KW      + kf*32 + lq*8];
    Wf1[kf] = *(const bfrag8*)&Wsrc[(size_t)(n0 + 16 + lj)*KW + kf*32 + lq*8];
  }
  floatx4 bi0 = {0,0,0,0}, bi1 = {0,0,0,0};
  if (IS1){
    bi0 = *(const floatx4*)&gb1[n0 + 4*a];
    bi1 = *(const floatx4*)&gb1[n0 + 16 + 4*a];
  }
  float c0s[4]={0,0,0,0}, c1s[4]={0,0,0,0};
  for (int it=0; it<=SS; ++it){
    const bool act = IS1 ? (it>=1) : (it<SS);
    if (act){
      const int t = IS1 ? it-1 : it;
      floatx4 aA0={0,0,0,0}, aB0={0,0,0,0}, aA1={0,0,0,0}, aB1={0,0,0,0};
      if (IS1 || t > 0){
        #pragma unroll
        for (int kf=0; kf<KF; ++kf){
          bool have = true;
          bfrag8 af = {};
          if (IS1){
            if (kf < 12)
              af = *(const bfrag8*)&h0r[(size_t)(t&1)*(BB*HG) + (m0+lj)*HG + kf*32 + lq*8];
            else if (t > 0)
              af = *(const bfrag8*)&h1seq[((size_t)(m0+lj)*SS + (t-1))*HG + (kf-12)*32 + lq*8];
            else have = false;          // h1[-1] = 0
          } else {
            af = *(const bfrag8*)&h0r[(size_t)((t-1)&1)*(BB*HG) + (m0+lj)*HG + kf*32 + lq*8];
          }
          if (have){
            if (kf & 1){ aB0 = MFMA16(af, Wf0[kf], aB0); aB1 = MFMA16(af, Wf1[kf], aB1); }
            else       { aA0 = MFMA16(af, Wf0[kf], aA0); aA1 = MFMA16(af, Wf1[kf], aA1); }
          }
        }
      }
      const floatx4 acc0 = aA0 + aB0, acc1 = aA1 + aB1;
      #pragma unroll
      for (int nt=0; nt<2; ++nt){
        #pragma unroll
        for (int r=0; r<4; ++r){
          float x = nt ? acc1[r] : acc0[r];
          // gather the quad's 4 gate values (cols 4a+0..3)
          float v0 = __shfl(x, (l & 60) | 0);
          float v1 = __shfl(x, (l & 60) | 1);
          float v2 = __shfl(x, (l & 60) | 2);
          float v3 = __shfl(x, (l & 60) | 3);
          int bb = m0 + 4*lq + r;
          int jh = bl*8 + nt*4 + a;    // global hidden index
          float pi,pf,pg,po;
          if (IS1){
            pi = v0 + (nt ? bi1[0] : bi0[0]);
            pf = v1 + (nt ? bi1[1] : bi0[1]);
            pg = v2 + (nt ? bi1[2] : bi0[2]);
            po = v3 + (nt ? bi1[3] : bi0[3]);
          } else {
            const ushort4 gv = *(const ushort4*)&G0t[((size_t)t*BB + bb)*G4 + n0 + nt*16 + 4*a];
            pi = v0 + b2f(gv.x); pf = v1 + b2f(gv.y); pg = v2 + b2f(gv.z); po = v3 + b2f(gv.w);
          }
          float i_=sigm_(pi), f_=sigm_(pf), g_=tanh_(pg), o_=sigm_(po);
          float cprev = nt ? c1s[r] : c0s[r];
          float c = f_*cprev + i_*g_;
          if (nt) c1s[r] = c; else c0s[r] = c;
          float h = o_*tanh_(c);
          if ((l&3) == 0){
            if (IS1) h1seq[((size_t)bb*SS + t)*HG + jh] = __float2bfloat16(h);
            else     h0r[(size_t)(t&1)*(BB*HG) + bb*HG + jh] = __float2bfloat16(h);
          }
        }
      }
    }
    grid_barrier(ctrs, it, bid, tid);
  }
}

__global__ __launch_bounds__(256,1) void graph_rnn(
    const bf16* __restrict__ G0t, const bf16* __restrict__ W0r, const bf16* __restrict__ W1c,
    const float* __restrict__ gb1, bf16* __restrict__ h0r, bf16* __restrict__ h1seq,
    unsigned int* ctrs)
{
  if (blockIdx.x < 48) rnn_body<0>(blockIdx.x, threadIdx.x, G0t, W0r, gb1, h0r, h1seq, ctrs);
  else                 rnn_body<1>(blockIdx.x, threadIdx.x, G0t, W1c, gb1, h0r, h1seq, ctrs);
}

// ---------------------------------------------------------------------------
// fused 2-layer edge LSTM, 33 steps, + cls dot, banded arc writeback.
// (unchanged from R1 — passed)
// ---------------------------------------------------------------------------
__global__ __launch_bounds__(256) void edge_lstm(
    const bf16* __restrict__ projb,
    const bf16* __restrict__ eW0b, const bf16* __restrict__ eW1ab, const bf16* __restrict__ eW1bb,
    const float* __restrict__ eb0, const float* __restrict__ eb1, const float* __restrict__ ew0c,
    const float* __restrict__ clsW, const float* __restrict__ clsb_p, const float* __restrict__ bos_p,
    const int* __restrict__ heads, float* __restrict__ arc)
{
  __shared__ alignas(16) bf16 hbuf0[16][72];
  __shared__ alignas(16) bf16 hbuf1[16][72];
  __shared__ float lbuf[4][16];
  const int tid = threadIdx.x, w = tid>>6, l = tid&63, lj = l&15, lq = l>>4;
  const int seq0 = blockIdx.x * 16;
  const int jglob = w*16 + lj;
  for (int i = tid; i < 16*64; i += 256){
    int sl = i >> 6, jj = i & 63;
    bf16 v = projb[(size_t)(seq0+sl)*HE + jj];
    hbuf0[sl][jj] = v; hbuf1[sl][jj] = v;
  }
  bfrag8 W0f[4][2], W1af[4][2], W1bf[4][2];
  #pragma unroll
  for (int g=0; g<4; ++g){
    #pragma unroll
    for (int kk=0; kk<2; ++kk){
      size_t offw = (size_t)(g*HE + jglob)*HE + kk*32 + lq*8;
      W0f [g][kk] = *(const bfrag8*)&eW0b [offw];
      W1af[g][kk] = *(const bfrag8*)&eW1ab[offw];
      W1bf[g][kk] = *(const bfrag8*)&eW1bb[offw];
    }
  }
  float ebr0[4], ebr1[4], ewr[4];
  #pragma unroll
  for (int g=0; g<4; ++g){ ebr0[g]=eb0[g*HE+jglob]; ebr1[g]=eb1[g*HE+jglob]; ewr[g]=ew0c[g*HE+jglob]; }
  const float clswj = clsW[jglob];
  const float bos = bos_p[0], clsb = clsb_p[0];
  int hd[4]; float c0r[4]={0,0,0,0}, c1r[4]={0,0,0,0};
  #pragma unroll
  for (int r=0;r<4;++r){
    int sq = seq0 + 4*lq + r;
    int b = sq >> 9, s = sq & 511;
    hd[r] = (s==0) ? 0 : heads[b*TT + s - 1];
  }
  __syncthreads();
  for (int j=0; j<33; ++j){
    floatx4 acc0[4] = {};
    bfrag8 a0[2];
    #pragma unroll
    for (int kk=0; kk<2; ++kk)
      a0[kk] = *(const bfrag8*)((const char*)&hbuf0[0][0] + lj*144 + kk*64 + lq*16);
    #pragma unroll
    for (int g=0; g<4; ++g)
      #pragma unroll
      for (int kk=0; kk<2; ++kk)
        acc0[g] = MFMA16(a0[kk], W0f[g][kk], acc0[g]);
    __syncthreads();
    float h0v[4];
    #pragma unroll
    for (int r=0;r<4;++r){
      float x = (j==0) ? bos : ((hd[r] == j-1) ? 1.f : 0.f);
      float pi = acc0[0][r] + ebr0[0] + x*ewr[0];
      float pf = acc0[1][r] + ebr0[1] + x*ewr[1];
      float pg = acc0[2][r] + ebr0[2] + x*ewr[2];
      float po = acc0[3][r] + ebr0[3] + x*ewr[3];
      float i_=sigm_(pi), f_=sigm_(pf), g_=tanh_(pg), o_=sigm_(po);
      c0r[r] = f_*c0r[r] + i_*g_;
      h0v[r] = o_*tanh_(c0r[r]);
    }
    #pragma unroll
    for (int r=0;r<4;++r) hbuf0[4*lq + r][jglob] = __float2bfloat16(h0v[r]);
    __syncthreads();
    floatx4 acc1[4] = {};
    bfrag8 a1[2], a2[2];
    #pragma unroll
    for (int kk=0;kk<2;++kk){
      a1[kk] = *(const bfrag8*)((const char*)&hbuf0[0][0] + lj*144 + kk*64 + lq*16);
      a2[kk] = *(const bfrag8*)((const char*)&hbuf1[0][0] + lj*144 + kk*64 + lq*16);
    }
    #pragma unroll
    for (int g=0; g<4; ++g){
      #pragma unroll
      for (int kk=0;kk<2;++kk){
        acc1[g] = MFMA16(a1[kk], W1af[g][kk], acc1[g]);
        acc1[g] = MFMA16(a2[kk], W1bf[g][kk], acc1[g]);
      }
    }
    __syncthreads();
    float p[4];
    #pragma unroll
    for (int r=0;r<4;++r){
      float pi = acc1[0][r] + ebr1[0];
      float pf = acc1[1][r] + ebr1[1];
      float pg = acc1[2][r] + ebr1[2];
      float po = acc1[3][r] + ebr1[3];
      float i_=sigm_(pi), f_=sigm_(pf), g_=tanh_(pg), o_=sigm_(po);
      c1r[r] = f_*c1r[r] + i_*g_;
      float h1 = o_*tanh_(c1r[r]);
      hbuf1[4*lq + r][jglob] = __float2bfloat16(h1);
      p[r] = h1 * clswj;
    }
    #pragma unroll
    for (int mk=1; mk<16; mk<<=1)
      #pragma unroll
      for (int r=0;r<4;++r) p[r] += __shfl_xor(p[r], mk, 64);
    if (lj == 0){
      #pragma unroll
      for (int r=0;r<4;++r) lbuf[w][4*lq + r] = p[r];
    }
    __syncthreads();
    if (tid < 16 && j >= 1){
      int sq = seq0 + tid;
      float v = lbuf[0][tid] + lbuf[1][tid] + lbuf[2][tid] + lbuf[3][tid] + clsb;
      arc[(size_t)sq*SS + (j-1)] = v;
    }
  }
}

// ---------------------------------------------------------------------------
extern "C" void kernel_launch(void* const* d_in, const int* in_sizes, int n_in,
                              void* d_out, int out_size, void* d_ws, size_t ws_size,
                              hipStream_t stream)
{
  const float* input = (const float*)d_in[0];
  const float* tag   = (const float*)d_in[1];
  const int*   mask  = (const int*)  d_in[2];
  const int*   heads = (const int*)  d_in[3];
  const float* sent  = (const float*)d_in[4];
  const float* bosp  = (const float*)d_in[5];
  const float* gWih0 = (const float*)d_in[6];
  const float* gWhh0 = (const float*)d_in[7];
  const float* gbih0 = (const float*)d_in[8];
  const float* gbhh0 = (const float*)d_in[9];
  const float* gWih1 = (const float*)d_in[10];
  const float* gWhh1 = (const float*)d_in[11];
  const float* gbih1 = (const float*)d_in[12];
  const float* gbhh1 = (const float*)d_in[13];
  const float* eWih0 = (const float*)d_in[14];
  const float* eWhh0 = (const float*)d_in[15];
  const float* ebih0 = (const float*)d_in[16];
  const float* ebhh0 = (const float*)d_in[17];
  const float* eWih1 = (const float*)d_in[18];
  const float* eWhh1 = (const float*)d_in[19];
  const float* ebih1 = (const float*)d_in[20];
  const float* ebhh1 = (const float*)d_in[21];
  const float* g2eW  = (const float*)d_in[22];
  const float* g2eb  = (const float*)d_in[23];
  const float* clsW  = (const float*)d_in[24];
  const float* clsb  = (const float*)d_in[25];
  const float* htW   = (const float*)d_in[26];
  const float* htb   = (const float*)d_in[27];
  const float* dtW   = (const float*)d_in[28];
  const float* dtb   = (const float*)d_in[29];

  char* wsb = (char*)d_ws;
  size_t off = 0;
  auto take = [&](size_t bytes)->char* {
    char* p = wsb + off;
    off = (off + bytes + 255) & ~(size_t)255;
    return p;
  };
  bf16*  Xb     = (bf16*) take((size_t)NSEQ*KXP*2);   // 33.6 MB
  bf16*  W0i    = (bf16*) take((size_t)G4*KXP*2);     // interleaved Wih0
  bf16*  W0r    = (bf16*) take((size_t)G4*HG*2);      // interleaved Whh0
  bf16*  W1c    = (bf16*) take((size_t)G4*768*2);     // interleaved [Wih1|Whh1]
  float* gb0i   = (float*)take(G4*4);
  float* gb1i   = (float*)take(G4*4);
  bf16*  G0t    = (bf16*) take((size_t)NSEQ*G4*2);    // 100.7 MB, time-major [t][b][1536]
  bf16*  h0ring = (bf16*) take((size_t)2*BB*HG*2);    // 2-slot h0 exchange ring
  bf16*  h1seq  = (bf16*) take((size_t)NSEQ*HG*2);    // 25.2 MB  [b][t][384]
  unsigned int* ctrs = (unsigned int*)take(8*64*4);   // grid-barrier counters
  bf16*  projb  = (bf16*) take((size_t)NSEQ*HE*2);
  bf16*  eW0b   = (bf16*) take(E4*HE*2);
  bf16*  eW1ab  = (bf16*) take(E4*HE*2);
  bf16*  eW1bb  = (bf16*) take(E4*HE*2);
  float* eb0w   = (float*)take(E4*4);
  float* eb1w   = (float*)take(E4*4);
  float* ew0cw  = (float*)take(E4*4);
  bf16*  g2eWb  = (bf16*) take(HE*HG*2);
  bf16*  htWb   = (bf16*) take(128*HG*2);
  bf16*  dtWb   = (bf16*) take(128*HG*2);

  (void)hipMemsetAsync(d_out, 0, (size_t)16777216*4, stream);
  (void)hipMemsetAsync(ctrs, 0, 8*64*4, stream);

  prep_x<<<2048,256,0,stream>>>(input, tag, sent, Xb);
  prep_w<<<512,256,0,stream>>>(gWih0,gWhh0,gbih0,gbhh0,gWih1,gWhh1,gbih1,gbhh1,
                               eWih0,eWhh0,ebih0,ebhh0,eWih1,eWhh1,ebih1,ebhh1,
                               g2eW,htW,dtW,
                               W0i,W0r,W1c,gb0i,gb1i,eW0b,eW1ab,eW1bb,
                               eb0w,eb1w,ew0cw,g2eWb,htWb,dtWb);

  // layer-0 input gates, time-major: G0t[t][b][:] = X@W0i^T + gb0
  gemm_mfma<KXP,128,2,2,3><<<3072,256,0,stream>>>(Xb, W0i, gb0i, nullptr, (void*)G0t, G4);

  // persistent 2-layer recurrence, 513 grid barriers
  graph_rnn<<<96,256,0,stream>>>(G0t, W0r, W1c, gb1i, h0ring, h1seq, ctrs);

  // proj = mask * (graph_state @ g2e_W^T) + g2e_b   -> bf16
  gemm_mfma<HG,64,4,1,1><<<256,256,0,stream>>>(h1seq, g2eWb, g2eb, mask, (void*)projb, HE);

  // banded teacher-forced edge LSTM + cls + arc writeback
  edge_lstm<<<2048,256,0,stream>>>(projb, eW0b, eW1ab, eW1bb, eb0w, eb1w, ew0cw,
                                   clsW, clsb, bosp, heads, (float*)d_out);

  // tag feedforwards: elu(mask*(graph_state @ W^T) + b)
  gemm_mfma<HG,128,2,2,2><<<256,256,0,stream>>>(h1seq, htWb, htb, mask,
      (void*)((float*)d_out + 16777216), 100);
  gemm_mfma<HG,128,2,2,2><<<256,256,0,stream>>>(h1seq, dtWb, dtb, mask,
      (void*)((float*)d_out + 16777216 + 3276800), 100);
}

// Round 3
// 5265.993 us; speedup vs baseline: 1.8146x; 1.3039x over previous
//
#include <hip/hip_runtime.h>
#include <hip/hip_bf16.h>
#include <stdint.h>

// ---------------- problem dims ----------------
#define BB   64
#define TT   511
#define SS   512
#define DD   500
#define KXP  512          // padded input dim for layer-0 input GEMM
#define HG   384
#define G4   1536
#define HE   64
#define E4   256
#define NSEQ (BB*SS)      // 32768

typedef __hip_bfloat16 bf16;
typedef float  floatx4 __attribute__((ext_vector_type(4)));
typedef __bf16 bfrag8  __attribute__((ext_vector_type(8)));

// v_mfma_f32_16x16x32_bf16 fragment layout (gfx950):
//   A: lane l holds A[l&15][8*(l>>4)+i]      (16B contiguous along K, A stored [M][K])
//   B: lane l holds W[n=l&15][8*(l>>4)+i]    (weights stored [N][K] = torch [out][in])
//   D: lane l, reg r holds D[4*(l>>4)+r][l&15]
static __device__ __forceinline__ floatx4 MFMA16(bfrag8 a, bfrag8 b, floatx4 c){
  return __builtin_amdgcn_mfma_f32_16x16x32_bf16(a, b, c, 0, 0, 0);
}
static __device__ __forceinline__ float sigm_(float x){ return 1.f/(1.f + __expf(-x)); }
static __device__ __forceinline__ float tanh_(float x){
  x = fminf(fmaxf(x, -15.f), 15.f);
  float e = __expf(2.f*x);
  return (e - 1.f)/(e + 1.f);
}
// per-lane gate activation: sigm for i,f,o; tanh via 2*sigm(2x)-1 for g. One exp per lane.
static __device__ __forceinline__ float actv(float x, bool isg){
  float s = 1.f/(1.f + __expf(isg ? -2.f*x : -x));
  return isg ? (2.f*s - 1.f) : s;
}
static __device__ __forceinline__ float b2f(unsigned short u){
  union { unsigned int i; float f; } x; x.i = ((unsigned int)u)<<16; return x.f;
}
static __device__ __forceinline__ unsigned short f2bu(float f){
  bf16 b = __float2bfloat16(f);
  return *reinterpret_cast<unsigned short*>(&b);
}

// ---- coherent (IC coherence-point) accesses for cross-block RNN state ----
static __device__ __forceinline__ bfrag8 ldfrag_coh(const bf16* p){
  unsigned long long u0 = __hip_atomic_load((unsigned long long*)p,     __ATOMIC_RELAXED, __HIP_MEMORY_SCOPE_SYSTEM);
  unsigned long long u1 = __hip_atomic_load((unsigned long long*)p + 1, __ATOMIC_RELAXED, __HIP_MEMORY_SCOPE_SYSTEM);
  union { unsigned long long u[2]; bfrag8 f; } x; x.u[0]=u0; x.u[1]=u1;
  return x.f;
}
static __device__ __forceinline__ void stpair_coh(bf16* p, float lo, float hi){
  unsigned int pk = (unsigned int)f2bu(lo) | ((unsigned int)f2bu(hi) << 16);
  __hip_atomic_store((unsigned int*)p, pk, __ATOMIC_RELAXED, __HIP_MEMORY_SCOPE_SYSTEM);
}
static __device__ __forceinline__ void pollge(unsigned int* p, unsigned int tgt){
  while (__hip_atomic_load(p, __ATOMIC_RELAXED, __HIP_MEMORY_SCOPE_AGENT) < tgt)
    __builtin_amdgcn_s_sleep(2);
}

// ---------------------------------------------------------------------------
// prep: build padded bf16 X = [sentinel ; concat(input, tag)]  -> [32768][512]
// ---------------------------------------------------------------------------
__global__ __launch_bounds__(256) void prep_x(const float* __restrict__ input,
    const float* __restrict__ tag, const float* __restrict__ sent,
    bf16* __restrict__ Xb)
{
  const size_t stp = (size_t)gridDim.x * blockDim.x;
  for (size_t i = (size_t)blockIdx.x*blockDim.x + threadIdx.x; i < (size_t)NSEQ*KXP; i += stp){
    int m = (int)(i >> 9), k = (int)(i & 511);
    int b = m >> 9, s = m & 511;
    float v;
    if (k >= DD)        v = 0.f;
    else if (s == 0)    v = sent[k];
    else if (k < 400)   v = input[(size_t)(b*TT + s-1)*400 + k];
    else                v = tag  [(size_t)(b*TT + s-1)*100 + (k-400)];
    Xb[i] = __float2bfloat16(v);
  }
}

// ---------------------------------------------------------------------------
// prep: weight conversions with gate interleave n=4j+g, bias folds
// ---------------------------------------------------------------------------
__global__ __launch_bounds__(256) void prep_w(
  const float* __restrict__ gWih0, const float* __restrict__ gWhh0,
  const float* __restrict__ gbih0, const float* __restrict__ gbhh0,
  const float* __restrict__ gWih1, const float* __restrict__ gWhh1,
  const float* __restrict__ gbih1, const float* __restrict__ gbhh1,
  const float* __restrict__ eWih0, const float* __restrict__ eWhh0,
  const float* __restrict__ ebih0, const float* __restrict__ ebhh0,
  const float* __restrict__ eWih1, const float* __restrict__ eWhh1,
  const float* __restrict__ ebih1, const float* __restrict__ ebhh1,
  const float* __restrict__ g2eW, const float* __restrict__ htW, const float* __restrict__ dtW,
  bf16* __restrict__ W0i, bf16* __restrict__ W0r, bf16* __restrict__ W1c,
  float* __restrict__ gb0, float* __restrict__ gb1,
  bf16* __restrict__ eW0b, bf16* __restrict__ eW1ab, bf16* __restrict__ eW1bb,
  float* __restrict__ eb0, float* __restrict__ eb1, float* __restrict__ ew0cv,
  bf16* __restrict__ g2eWb, bf16* __restrict__ htWb, bf16* __restrict__ dtWb)
{
  const int st = blockIdx.x*blockDim.x + threadIdx.x;
  const int gs = gridDim.x*blockDim.x;
  // layer-0 input weights, rows interleaved n=4j+g, K padded to 512
  for (int i=st; i<G4*KXP; i+=gs){ int n=i>>9, k=i&511; int j=n>>2, g=n&3;
      W0i[i] = __float2bfloat16(k<DD ? gWih0[(size_t)(g*HG+j)*DD+k] : 0.f); }
  // layer-0 recurrent weights interleaved [1536][384]
  for (int i=st; i<G4*HG; i+=gs){ int n=i/HG, k=i-n*HG; int j=n>>2, g=n&3;
      W0r[i] = __float2bfloat16(gWhh0[(size_t)(g*HG+j)*HG+k]); }
  // layer-1 concat [Wih1|Whh1] interleaved [1536][768]
  for (int i=st; i<G4*768; i+=gs){ int n=i/768, k=i-n*768; int j=n>>2, g=n&3;
      W1c[i] = __float2bfloat16(k<HG ? gWih1[(size_t)(g*HG+j)*HG+k]
                                     : gWhh1[(size_t)(g*HG+j)*HG+(k-HG)]); }
  for (int i=st; i<G4; i+=gs){ int j=i>>2, g=i&3; int s=g*HG+j;
      gb0[i]=gbih0[s]+gbhh0[s]; gb1[i]=gbih1[s]+gbhh1[s]; }
  // edge LSTM weights (layouts unchanged)
  for (int i=st; i<E4*HE; i+=gs){ eW0b[i]=__float2bfloat16(eWhh0[i]);
      eW1ab[i]=__float2bfloat16(eWih1[i]); eW1bb[i]=__float2bfloat16(eWhh1[i]); }
  for (int i=st; i<E4; i+=gs){ eb0[i]=ebih0[i]+ebhh0[i]; eb1[i]=ebih1[i]+ebhh1[i];
      ew0cv[i]=eWih0[i]; }
  for (int i=st; i<HE*HG; i+=gs) g2eWb[i]=__float2bfloat16(g2eW[i]);
  for (int i=st; i<128*HG; i+=gs){
      htWb[i] = __float2bfloat16(i<100*HG ? htW[i] : 0.f);
      dtWb[i] = __float2bfloat16(i<100*HG ? dtW[i] : 0.f); }
}

// ---------------------------------------------------------------------------
// generic MFMA GEMM:  out[M][N] = epi( A[M][KTOT] @ Wt[N][KTOT]^T )
//   EPI 0: +bias, store bf16 (ld=Nreal)
//   EPI 3: +bias, store bf16 TRANSPOSED time-major: out[(s*64+b)*1536 + col]
//   EPI 1: *maskrow +bias, store bf16
//   EPI 2: *maskrow +bias, elu, store f32, guard col<Nreal
// ---------------------------------------------------------------------------
template<int KTOT,int BN,int WAVES_M,int WAVES_N,int EPI>
__global__ __launch_bounds__(256) void gemm_mfma(
    const bf16* __restrict__ A, const bf16* __restrict__ Wt,
    const float* __restrict__ bias, const int* __restrict__ mask,
    void* __restrict__ outp, int Nreal)
{
  constexpr int WMT = 128/(WAVES_M*16);
  constexpr int WNT = BN /(WAVES_N*16);
  __shared__ alignas(16) bf16 As[128][32];
  __shared__ alignas(16) bf16 Bs[BN][32];
  const int tid = threadIdx.x;
  const int bm = blockIdx.x & 255, bn = blockIdx.x >> 8;
  const int m0 = bm*128, n0 = bn*BN;
  const int wid = tid>>6, l = tid&63, lj = l&15, lq = l>>4;
  const int wm = wid / WAVES_N, wn = wid % WAVES_N;
  floatx4 acc[WMT][WNT] = {};
  for (int k0 = 0; k0 < KTOT; k0 += 32){
    __syncthreads();
    for (int c = tid; c < 128*4; c += 256){
      int row = c>>2, ch = c&3;
      *(uint4*)&As[row][ch*8] = *(const uint4*)&A[(size_t)(m0+row)*KTOT + k0 + ch*8];
    }
    for (int c = tid; c < BN*4; c += 256){
      int row = c>>2, ch = c&3;
      *(uint4*)&Bs[row][ch*8] = *(const uint4*)&Wt[(size_t)(n0+row)*KTOT + k0 + ch*8];
    }
    __syncthreads();
    bfrag8 af[WMT]; bfrag8 bfr[WNT];
    #pragma unroll
    for (int mi=0;mi<WMT;++mi) af[mi]  = *(const bfrag8*)&As[wm*WMT*16 + mi*16 + lj][lq*8];
    #pragma unroll
    for (int ni=0;ni<WNT;++ni) bfr[ni] = *(const bfrag8*)&Bs[wn*WNT*16 + ni*16 + lj][lq*8];
    #pragma unroll
    for (int mi=0;mi<WMT;++mi)
      #pragma unroll
      for (int ni=0;ni<WNT;++ni)
        acc[mi][ni] = MFMA16(af[mi], bfr[ni], acc[mi][ni]);
  }
  #pragma unroll
  for (int mi=0;mi<WMT;++mi){
    #pragma unroll
    for (int ni=0;ni<WNT;++ni){
      #pragma unroll
      for (int r=0;r<4;++r){
        int grow = m0 + wm*WMT*16 + mi*16 + 4*lq + r;
        int gcol = n0 + wn*WNT*16 + ni*16 + lj;
        float v = acc[mi][ni][r];
        if (EPI == 0){
          v += bias[gcol];
          ((bf16*)outp)[(size_t)grow*Nreal + gcol] = __float2bfloat16(v);
        } else if (EPI == 3){
          v += bias[gcol];
          int s = grow & 511, b = grow >> 9;
          ((bf16*)outp)[((size_t)s*BB + b)*G4 + gcol] = __float2bfloat16(v);
        } else {
          int s = grow & 511, b = grow >> 9;
          float mk = (s==0) ? 1.f : (float)mask[b*TT + s - 1];
          v = v*mk + bias[gcol];
          if (EPI == 1){
            ((bf16*)outp)[(size_t)grow*Nreal + gcol] = __float2bfloat16(v);
          } else {
            v = v > 0.f ? v : expm1f(v);
            if (gcol < Nreal) ((float*)outp)[(size_t)grow*Nreal + gcol] = v;
          }
        }
      }
    }
  }
}

// ---------------------------------------------------------------------------
// persistent graph-LSTM recurrence, decoupled-counter version.
// blocks 0..47 layer0 (round it computes t=it, rounds 0..511)
// blocks 48..95 layer1 (round it computes t=it-1, rounds 0..512)
// Cross-block state (h0 ring [4 slots], h1seq) uses per-access coherent
// atomics (sc0+sc1) -> NO cache-flush fences anywhere.
// ctr0 lines ctrs[0..3]*64 (layer0 arrivals, 12 blocks/line, +1 per round)
// ctr1 lines ctrs[4..7]*64 (layer1 arrivals)
// "group finished round u" <=> line >= 12*(u+1).
// Waits at round it:
//   L0: ctr0 >= 12*it (h0(it-1) ready); ctr1 >= 12*(it-2) (ring backpressure, it>=3)
//   L1: ctr0 >= 12*it (h0(it-1) ready); ctr1 >= 12*it (own h1(it-2) cols, it>=2)
// ---------------------------------------------------------------------------
template<int IS1>
__device__ __forceinline__ void rnn_body(int bid, int tid,
    const bf16* __restrict__ G0t, const bf16* __restrict__ Wsrc,
    const float* __restrict__ gb1,
    bf16* __restrict__ h0r, bf16* __restrict__ h1seq, unsigned int* __restrict__ ctrs)
{
  constexpr int KW = IS1 ? 768 : 384;
  const int bl = IS1 ? bid-48 : bid;
  const int w = tid>>6, l = tid&63, lj = l&15, lq = l>>4;
  const int m0 = w*16;          // wave = batch tile
  const int n0 = bl*32;         // block's 2 N-tiles: gate cols [n0, n0+32)
  const int a  = lj>>2;         // hidden index within 4-wide quad group
  const int gl = l&3;           // gate owned by this lane (i,f,g,o)
  const bool isg = (gl==2);

  // recurrent weights in registers / L2-hot remat
  constexpr int KF = IS1 ? 24 : 12;
  bfrag8 Wf0[KF], Wf1[KF];
  #pragma unroll
  for (int kf=0; kf<KF; ++kf){
    Wf0[kf] = *(const bfrag8*)&Wsrc[(size_t)(n0 + lj)*KW      + kf*32 + lq*8];
    Wf1[kf] = *(const bfrag8*)&Wsrc[(size_t)(n0 + 16 + lj)*KW + kf*32 + lq*8];
  }
  float bi0 = 0.f, bi1 = 0.f;
  if (IS1){ bi0 = gb1[n0 + 4*a + gl]; bi1 = gb1[n0 + 16 + 4*a + gl]; }

  float c0s[4]={0,0,0,0}, c1s[4]={0,0,0,0};
  unsigned short g0pre[2][4];
  if (!IS1){
    #pragma unroll
    for (int nt=0;nt<2;++nt)
      #pragma unroll
      for (int r=0;r<4;++r){
        int bb = m0 + 4*lq + r;
        g0pre[nt][r] = *(const unsigned short*)&G0t[(size_t)bb*G4 + n0 + nt*16 + 4*a + gl];
      }
  }
  const int ITMAX = IS1 ? SS : (SS-1);
  for (int it=0; it<=ITMAX; ++it){
    // ---- wait phase ----
    if (it > 0){
      if (tid < 4){
        pollge(&ctrs[tid*64], 12u*(unsigned)it);
      } else if (tid < 8){
        if (IS1){ if (it >= 2) pollge(&ctrs[tid*64], 12u*(unsigned)it); }
        else    { if (it >= 3) pollge(&ctrs[tid*64], 12u*(unsigned)(it-2)); }
      }
      __syncthreads();
    }
    // ---- compute phase ----
    if (!IS1 || it >= 1){
      const int t = IS1 ? it-1 : it;
      floatx4 aA0={0,0,0,0}, aB0={0,0,0,0}, aA1={0,0,0,0}, aB1={0,0,0,0};
      if (IS1){
        const bf16* hb0 = h0r + (size_t)((it-1)&3)*(BB*HG) + (size_t)(m0+lj)*HG;
        #pragma unroll
        for (int kf=0; kf<12; ++kf){
          bfrag8 af = ldfrag_coh(hb0 + kf*32 + lq*8);
          if (kf&1){ aB0 = MFMA16(af, Wf0[kf], aB0); aB1 = MFMA16(af, Wf1[kf], aB1); }
          else     { aA0 = MFMA16(af, Wf0[kf], aA0); aA1 = MFMA16(af, Wf1[kf], aA1); }
        }
        if (t > 0){
          const bf16* hb1 = h1seq + ((size_t)(m0+lj)*SS + (t-1))*HG;
          #pragma unroll
          for (int kf=12; kf<24; ++kf){
            bfrag8 af = ldfrag_coh(hb1 + (kf-12)*32 + lq*8);
            if (kf&1){ aB0 = MFMA16(af, Wf0[kf], aB0); aB1 = MFMA16(af, Wf1[kf], aB1); }
            else     { aA0 = MFMA16(af, Wf0[kf], aA0); aA1 = MFMA16(af, Wf1[kf], aA1); }
          }
        }
      } else if (t > 0){
        const bf16* hb = h0r + (size_t)((t-1)&3)*(BB*HG) + (size_t)(m0+lj)*HG;
        #pragma unroll
        for (int kf=0; kf<12; ++kf){
          bfrag8 af = ldfrag_coh(hb + kf*32 + lq*8);
          if (kf&1){ aB0 = MFMA16(af, Wf0[kf], aB0); aB1 = MFMA16(af, Wf1[kf], aB1); }
          else     { aA0 = MFMA16(af, Wf0[kf], aA0); aA1 = MFMA16(af, Wf1[kf], aA1); }
        }
      }
      const floatx4 s0 = aA0 + aB0, s1 = aA1 + aB1;
      #pragma unroll
      for (int nt=0; nt<2; ++nt){
        #pragma unroll
        for (int r=0; r<4; ++r){
          float x = nt ? s1[r] : s0[r];
          x += IS1 ? (nt ? bi1 : bi0) : b2f(g0pre[nt][r]);
          float av = actv(x, isg);            // own gate only
          float i_ = __shfl(av, (l&60)|0);
          float f_ = __shfl(av, (l&60)|1);
          float g_ = __shfl(av, (l&60)|2);
          float o_ = __shfl(av, (l&60)|3);
          float cp = nt ? c1s[r] : c0s[r];
          float c = f_*cp + i_*g_;
          if (nt) c1s[r] = c; else c0s[r] = c;
          float h = o_*tanh_(c);
          float hn = __shfl(h, l^4);          // neighbor quad's h (a+1)
          if ((l&7) == 0){
            int bb = m0 + 4*lq + r;
            int jh = bl*8 + nt*4 + a;         // a even here
            bf16* hp = IS1 ? (h1seq + ((size_t)bb*SS + t)*HG + jh)
                           : (h0r + (size_t)(t&3)*(BB*HG) + (size_t)bb*HG + jh);
            stpair_coh(hp, h, hn);
          }
        }
      }
      // prefetch next step's G0 pre-acts (independent of barrier)
      if (!IS1 && it+1 < SS){
        #pragma unroll
        for (int nt=0;nt<2;++nt)
          #pragma unroll
          for (int r=0;r<4;++r){
            int bb = m0 + 4*lq + r;
            g0pre[nt][r] = *(const unsigned short*)&G0t[((size_t)(it+1)*BB + bb)*G4 + n0 + nt*16 + 4*a + gl];
          }
      }
    }
    // ---- signal phase ----
    asm volatile("s_waitcnt vmcnt(0) lgkmcnt(0)" ::: "memory");
    __syncthreads();
    if (tid == 0)
      __hip_atomic_fetch_add(&ctrs[((IS1?4:0) + (bl&3))*64], 1u,
                             __ATOMIC_RELAXED, __HIP_MEMORY_SCOPE_AGENT);
  }
}

__global__ __launch_bounds__(256,1) void graph_rnn(
    const bf16* __restrict__ G0t, const bf16* __restrict__ W0r, const bf16* __restrict__ W1c,
    const float* __restrict__ gb1, bf16* __restrict__ h0r, bf16* __restrict__ h1seq,
    unsigned int* ctrs)
{
  if (blockIdx.x < 48) rnn_body<0>(blockIdx.x, threadIdx.x, G0t, W0r, gb1, h0r, h1seq, ctrs);
  else                 rnn_body<1>(blockIdx.x, threadIdx.x, G0t, W1c, gb1, h0r, h1seq, ctrs);
}

// ---------------------------------------------------------------------------
// fused 2-layer edge LSTM, 33 steps, + cls dot, banded arc writeback.
// ---------------------------------------------------------------------------
__global__ __launch_bounds__(256) void edge_lstm(
    const bf16* __restrict__ projb,
    const bf16* __restrict__ eW0b, const bf16* __restrict__ eW1ab, const bf16* __restrict__ eW1bb,
    const float* __restrict__ eb0, const float* __restrict__ eb1, const float* __restrict__ ew0c,
    const float* __restrict__ clsW, const float* __restrict__ clsb_p, const float* __restrict__ bos_p,
    const int* __restrict__ heads, float* __restrict__ arc)
{
  __shared__ alignas(16) bf16 hbuf0[16][72];
  __shared__ alignas(16) bf16 hbuf1[16][72];
  __shared__ float lbuf[4][16];
  const int tid = threadIdx.x, w = tid>>6, l = tid&63, lj = l&15, lq = l>>4;
  const int seq0 = blockIdx.x * 16;
  const int jglob = w*16 + lj;
  for (int i = tid; i < 16*64; i += 256){
    int sl = i >> 6, jj = i & 63;
    bf16 v = projb[(size_t)(seq0+sl)*HE + jj];
    hbuf0[sl][jj] = v; hbuf1[sl][jj] = v;
  }
  bfrag8 W0f[4][2], W1af[4][2], W1bf[4][2];
  #pragma unroll
  for (int g=0; g<4; ++g){
    #pragma unroll
    for (int kk=0; kk<2; ++kk){
      size_t offw = (size_t)(g*HE + jglob)*HE + kk*32 + lq*8;
      W0f [g][kk] = *(const bfrag8*)&eW0b [offw];
      W1af[g][kk] = *(const bfrag8*)&eW1ab[offw];
      W1bf[g][kk] = *(const bfrag8*)&eW1bb[offw];
    }
  }
  float ebr0[4], ebr1[4], ewr[4];
  #pragma unroll
  for (int g=0; g<4; ++g){ ebr0[g]=eb0[g*HE+jglob]; ebr1[g]=eb1[g*HE+jglob]; ewr[g]=ew0c[g*HE+jglob]; }
  const float clswj = clsW[jglob];
  const float bos = bos_p[0], clsb = clsb_p[0];
  int hd[4]; float c0r[4]={0,0,0,0}, c1r[4]={0,0,0,0};
  #pragma unroll
  for (int r=0;r<4;++r){
    int sq = seq0 + 4*lq + r;
    int b = sq >> 9, s = sq & 511;
    hd[r] = (s==0) ? 0 : heads[b*TT + s - 1];
  }
  __syncthreads();
  for (int j=0; j<33; ++j){
    floatx4 acc0[4] = {};
    bfrag8 a0[2];
    #pragma unroll
    for (int kk=0; kk<2; ++kk)
      a0[kk] = *(const bfrag8*)((const char*)&hbuf0[0][0] + lj*144 + kk*64 + lq*16);
    #pragma unroll
    for (int g=0; g<4; ++g)
      #pragma unroll
      for (int kk=0; kk<2; ++kk)
        acc0[g] = MFMA16(a0[kk], W0f[g][kk], acc0[g]);
    __syncthreads();
    float h0v[4];
    #pragma unroll
    for (int r=0;r<4;++r){
      float x = (j==0) ? bos : ((hd[r] == j-1) ? 1.f : 0.f);
      float pi = acc0[0][r] + ebr0[0] + x*ewr[0];
      float pf = acc0[1][r] + ebr0[1] + x*ewr[1];
      float pg = acc0[2][r] + ebr0[2] + x*ewr[2];
      float po = acc0[3][r] + ebr0[3] + x*ewr[3];
      float i_=sigm_(pi), f_=sigm_(pf), g_=tanh_(pg), o_=sigm_(po);
      c0r[r] = f_*c0r[r] + i_*g_;
      h0v[r] = o_*tanh_(c0r[r]);
    }
    #pragma unroll
    for (int r=0;r<4;++r) hbuf0[4*lq + r][jglob] = __float2bfloat16(h0v[r]);
    __syncthreads();
    floatx4 acc1[4] = {};
    bfrag8 a1[2], a2[2];
    #pragma unroll
    for (int kk=0;kk<2;++kk){
      a1[kk] = *(const bfrag8*)((const char*)&hbuf0[0][0] + lj*144 + kk*64 + lq*16);
      a2[kk] = *(const bfrag8*)((const char*)&hbuf1[0][0] + lj*144 + kk*64 + lq*16);
    }
    #pragma unroll
    for (int g=0; g<4; ++g){
      #pragma unroll
      for (int kk=0;kk<2;++kk){
        acc1[g] = MFMA16(a1[kk], W1af[g][kk], acc1[g]);
        acc1[g] = MFMA16(a2[kk], W1bf[g][kk], acc1[g]);
      }
    }
    __syncthreads();
    float p[4];
    #pragma unroll
    for (int r=0;r<4;++r){
      float pi = acc1[0][r] + ebr1[0];
      float pf = acc1[1][r] + ebr1[1];
      float pg = acc1[2][r] + ebr1[2];
      float po = acc1[3][r] + ebr1[3];
      float i_=sigm_(pi), f_=sigm_(pf), g_=tanh_(pg), o_=sigm_(po);
      c1r[r] = f_*c1r[r] + i_*g_;
      float h1 = o_*tanh_(c1r[r]);
      hbuf1[4*lq + r][jglob] = __float2bfloat16(h1);
      p[r] = h1 * clswj;
    }
    #pragma unroll
    for (int mk=1; mk<16; mk<<=1)
      #pragma unroll
      for (int r=0;r<4;++r) p[r] += __shfl_xor(p[r], mk, 64);
    if (lj == 0){
      #pragma unroll
      for (int r=0;r<4;++r) lbuf[w][4*lq + r] = p[r];
    }
    __syncthreads();
    if (tid < 16 && j >= 1){
      int sq = seq0 + tid;
      float v = lbuf[0][tid] + lbuf[1][tid] + lbuf[2][tid] + lbuf[3][tid] + clsb;
      arc[(size_t)sq*SS + (j-1)] = v;
    }
  }
}

// ---------------------------------------------------------------------------
extern "C" void kernel_launch(void* const* d_in, const int* in_sizes, int n_in,
                              void* d_out, int out_size, void* d_ws, size_t ws_size,
                              hipStream_t stream)
{
  const float* input = (const float*)d_in[0];
  const float* tag   = (const float*)d_in[1];
  const int*   mask  = (const int*)  d_in[2];
  const int*   heads = (const int*)  d_in[3];
  const float* sent  = (const float*)d_in[4];
  const float* bosp  = (const float*)d_in[5];
  const float* gWih0 = (const float*)d_in[6];
  const float* gWhh0 = (const float*)d_in[7];
  const float* gbih0 = (const float*)d_in[8];
  const float* gbhh0 = (const float*)d_in[9];
  const float* gWih1 = (const float*)d_in[10];
  const float* gWhh1 = (const float*)d_in[11];
  const float* gbih1 = (const float*)d_in[12];
  const float* gbhh1 = (const float*)d_in[13];
  const float* eWih0 = (const float*)d_in[14];
  const float* eWhh0 = (const float*)d_in[15];
  const float* ebih0 = (const float*)d_in[16];
  const float* ebhh0 = (const float*)d_in[17];
  const float* eWih1 = (const float*)d_in[18];
  const float* eWhh1 = (const float*)d_in[19];
  const float* ebih1 = (const float*)d_in[20];
  const float* ebhh1 = (const float*)d_in[21];
  const float* g2eW  = (const float*)d_in[22];
  const float* g2eb  = (const float*)d_in[23];
  const float* clsW  = (const float*)d_in[24];
  const float* clsb  = (const float*)d_in[25];
  const float* htW   = (const float*)d_in[26];
  const float* htb   = (const float*)d_in[27];
  const float* dtW   = (const float*)d_in[28];
  const float* dtb   = (const float*)d_in[29];

  char* wsb = (char*)d_ws;
  size_t off = 0;
  auto take = [&](size_t bytes)->char* {
    char* p = wsb + off;
    off = (off + bytes + 255) & ~(size_t)255;
    return p;
  };
  bf16*  Xb     = (bf16*) take((size_t)NSEQ*KXP*2);   // 33.6 MB
  bf16*  W0i    = (bf16*) take((size_t)G4*KXP*2);     // interleaved Wih0
  bf16*  W0r    = (bf16*) take((size_t)G4*HG*2);      // interleaved Whh0
  bf16*  W1c    = (bf16*) take((size_t)G4*768*2);     // interleaved [Wih1|Whh1]
  float* gb0i   = (float*)take(G4*4);
  float* gb1i   = (float*)take(G4*4);
  bf16*  G0t    = (bf16*) take((size_t)NSEQ*G4*2);    // 100.7 MB, time-major [t][b][1536]
  bf16*  h0ring = (bf16*) take((size_t)4*BB*HG*2);    // 4-slot h0 exchange ring
  bf16*  h1seq  = (bf16*) take((size_t)NSEQ*HG*2);    // 25.2 MB  [b][t][384]
  unsigned int* ctrs = (unsigned int*)take(8*64*4);   // arrival counters
  bf16*  projb  = (bf16*) take((size_t)NSEQ*HE*2);
  bf16*  eW0b   = (bf16*) take(E4*HE*2);
  bf16*  eW1ab  = (bf16*) take(E4*HE*2);
  bf16*  eW1bb  = (bf16*) take(E4*HE*2);
  float* eb0w   = (float*)take(E4*4);
  float* eb1w   = (float*)take(E4*4);
  float* ew0cw  = (float*)take(E4*4);
  bf16*  g2eWb  = (bf16*) take(HE*HG*2);
  bf16*  htWb   = (bf16*) take(128*HG*2);
  bf16*  dtWb   = (bf16*) take(128*HG*2);

  (void)hipMemsetAsync(d_out, 0, (size_t)16777216*4, stream);
  (void)hipMemsetAsync(ctrs, 0, 8*64*4, stream);

  prep_x<<<2048,256,0,stream>>>(input, tag, sent, Xb);
  prep_w<<<512,256,0,stream>>>(gWih0,gWhh0,gbih0,gbhh0,gWih1,gWhh1,gbih1,gbhh1,
                               eWih0,eWhh0,ebih0,ebhh0,eWih1,eWhh1,ebih1,ebhh1,
                               g2eW,htW,dtW,
                               W0i,W0r,W1c,gb0i,gb1i,eW0b,eW1ab,eW1bb,
                               eb0w,eb1w,ew0cw,g2eWb,htWb,dtWb);

  // layer-0 input gates, time-major: G0t[t][b][:] = X@W0i^T + gb0
  gemm_mfma<KXP,128,2,2,3><<<3072,256,0,stream>>>(Xb, W0i, gb0i, nullptr, (void*)G0t, G4);

  // persistent 2-layer recurrence, decoupled counters, no cache flushes
  graph_rnn<<<96,256,0,stream>>>(G0t, W0r, W1c, gb1i, h0ring, h1seq, ctrs);

  // proj = mask * (graph_state @ g2e_W^T) + g2e_b   -> bf16
  gemm_mfma<HG,64,4,1,1><<<256,256,0,stream>>>(h1seq, g2eWb, g2eb, mask, (void*)projb, HE);

  // banded teacher-forced edge LSTM + cls + arc writeback
  edge_lstm<<<2048,256,0,stream>>>(projb, eW0b, eW1ab, eW1bb, eb0w, eb1w, ew0cw,
                                   clsW, clsb, bosp, heads, (float*)d_out);

  // tag feedforwards: elu(mask*(graph_state @ W^T) + b)
  gemm_mfma<HG,128,2,2,2><<<256,256,0,stream>>>(h1seq, htWb, htb, mask,
      (void*)((float*)d_out + 16777216), 100);
  gemm_mfma<HG,128,2,2,2><<<256,256,0,stream>>>(h1seq, dtWb, dtb, mask,
      (void*)((float*)d_out + 16777216 + 3276800), 100);
}